// Round 3
// baseline (286.329 us; speedup 1.0000x reference)
//
#include <hip/hip_runtime.h>
#include <hip/hip_bf16.h>

typedef __attribute__((ext_vector_type(8))) short bf16x8;
typedef __attribute__((ext_vector_type(4))) float f32x4;

#define BM 128
#define BN 128
#define BK 64
#define NTHREADS 256
#define MTOT 65536

__device__ __forceinline__ short f2bf_s(float f) {
    __hip_bfloat16 b = __float2bfloat16(f);
    return *reinterpret_cast<short*>(&b);
}

__global__ __launch_bounds__(NTHREADS)
void dft256_kernel(const float* __restrict__ xr, const float* __restrict__ xi,
                   const float* __restrict__ wr, const float* __restrict__ wi,
                   float* __restrict__ out)
{
    // bf16 tiles, XOR-swizzled in 16B slots: slot = (row*8 + seg) ^ (row&7)
    __shared__ __align__(16) char sA[BM * BK * 2]; // A[row 0..127][k 0..63]
    __shared__ __align__(16) char sB[BN * BK * 2]; // Bt[n 0..127][k 0..63]

    const int tid  = threadIdx.x;
    const int lane = tid & 63;
    const int wv   = tid >> 6;
    const int wrow = wv >> 1;      // wave row 0..1 (64 M-rows each)
    const int wcol = wv & 1;       // wave col 0..1 (64 N-cols each)
    const int fr   = lane & 15;    // fragment row (A) / col (B) / col (C)
    const int rg   = lane >> 4;    // k-group (in), row-group (out)

    const int nb = blockIdx.x & 3;     // 4 N-blocks over combined N=512
    const int mb = blockIdx.x >> 2;    // 512 M-blocks
    const int m0 = mb * BM;
    const int part = nb >> 1;          // 0 = out_r, 1 = out_i
    const int h0 = (nb & 1) * BN;      // column offset within the 256 h-dim

    f32x4 acc[4][4];
#pragma unroll
    for (int i = 0; i < 4; ++i)
#pragma unroll
        for (int j = 0; j < 4; ++j)
            acc[i][j] = (f32x4){0.f, 0.f, 0.f, 0.f};

    const int srow = tid >> 3;   // staging row base 0..31 (+32 per pass)
    const int sseg = tid & 7;    // 8-float segment within row

    for (int ks = 0; ks < 8; ++ks) {
        const int k0 = ks * BK;          // combined-K offset, 0..448
        const int kc = k0 & 255;         // offset within each 256 half
        const float* asrc = (k0 < 256) ? xr : xi;
        const float* bsrc;
        float bsign = 1.0f;
        if (part == 0) {                 // out_r = x_r*w_r - x_i*w_i
            if (k0 < 256) { bsrc = wr; } else { bsrc = wi; bsign = -1.0f; }
        } else {                         // out_i = x_r*w_i + x_i*w_r
            bsrc = (k0 < 256) ? wi : wr;
        }

        __syncthreads();   // previous iter's reads done before overwrite

        // ---- stage A: 128 rows x 64 k fp32 -> bf16, swizzled ----
#pragma unroll
        for (int p = 0; p < 4; ++p) {
            const int row = srow + p * 32;
            const float* g = asrc + (size_t)(m0 + row) * 256 + kc + sseg * 8;
            f32x4 v0 = *(const f32x4*)g;
            f32x4 v1 = *(const f32x4*)(g + 4);
            bf16x8 hv;
            hv[0] = f2bf_s(v0[0]); hv[1] = f2bf_s(v0[1]);
            hv[2] = f2bf_s(v0[2]); hv[3] = f2bf_s(v0[3]);
            hv[4] = f2bf_s(v1[0]); hv[5] = f2bf_s(v1[1]);
            hv[6] = f2bf_s(v1[2]); hv[7] = f2bf_s(v1[3]);
            const int slot = (row * 8 + sseg) ^ (row & 7);
            *(bf16x8*)(sA + slot * 16) = hv;
        }
        // ---- stage Bt: 128 n-rows x 64 k fp32 -> bf16 (signed), swizzled ----
#pragma unroll
        for (int p = 0; p < 4; ++p) {
            const int row = srow + p * 32;
            const float* g = bsrc + (size_t)(h0 + row) * 256 + kc + sseg * 8;
            f32x4 v0 = *(const f32x4*)g;
            f32x4 v1 = *(const f32x4*)(g + 4);
            bf16x8 hv;
            hv[0] = f2bf_s(bsign * v0[0]); hv[1] = f2bf_s(bsign * v0[1]);
            hv[2] = f2bf_s(bsign * v0[2]); hv[3] = f2bf_s(bsign * v0[3]);
            hv[4] = f2bf_s(bsign * v1[0]); hv[5] = f2bf_s(bsign * v1[1]);
            hv[6] = f2bf_s(bsign * v1[2]); hv[7] = f2bf_s(bsign * v1[3]);
            const int slot = (row * 8 + sseg) ^ (row & 7);
            *(bf16x8*)(sB + slot * 16) = hv;
        }

        __syncthreads();

        // ---- compute: 2 x (8 ds_read_b128 + 16 MFMA) ----
#pragma unroll
        for (int kk = 0; kk < 2; ++kk) {
            const int kbyte = kk * 64 + rg * 16;
            bf16x8 av[4], bv[4];
#pragma unroll
            for (int i = 0; i < 4; ++i) {
                const int row = wrow * 64 + i * 16 + fr;
                av[i] = *(const bf16x8*)(sA + ((row * 128 + kbyte) ^ ((row & 7) << 4)));
            }
#pragma unroll
            for (int j = 0; j < 4; ++j) {
                const int row = wcol * 64 + j * 16 + fr;
                bv[j] = *(const bf16x8*)(sB + ((row * 128 + kbyte) ^ ((row & 7) << 4)));
            }
#pragma unroll
            for (int i = 0; i < 4; ++i)
#pragma unroll
                for (int j = 0; j < 4; ++j)
                    acc[i][j] = __builtin_amdgcn_mfma_f32_16x16x32_bf16(
                        av[i], bv[j], acc[i][j], 0, 0, 0);
        }
    }

    // ---- epilogue: C/D layout col=lane&15, row=(lane>>4)*4+reg ----
    float* obase = out + (size_t)part * ((size_t)MTOT * 256);
#pragma unroll
    for (int i = 0; i < 4; ++i) {
#pragma unroll
        for (int j = 0; j < 4; ++j) {
            const int row = m0 + wrow * 64 + i * 16 + rg * 4;
            const int h = h0 + wcol * 64 + j * 16 + fr;
            float* o = obase + (size_t)row * 256 + h;
#pragma unroll
            for (int r = 0; r < 4; ++r)
                o[(size_t)r * 256] = acc[i][j][r];
        }
    }
}

extern "C" void kernel_launch(void* const* d_in, const int* in_sizes, int n_in,
                              void* d_out, int out_size, void* d_ws, size_t ws_size,
                              hipStream_t stream) {
    const float* xr = (const float*)d_in[0];
    const float* xi = (const float*)d_in[1];
    const float* wr = (const float*)d_in[2];
    const float* wi = (const float*)d_in[3];
    float* out = (float*)d_out;
    dim3 grid((MTOT / BM) * 4);   // 512 M-blocks x 4 N-blocks = 2048
    dft256_kernel<<<grid, NTHREADS, 0, stream>>>(xr, xi, wr, wi, out);
}